// Round 14
// baseline (382.883 us; speedup 1.0000x reference)
//
#include <hip/hip_runtime.h>
#include <hip/hip_bf16.h>

// MindSpeedTEGroupedLinear: 64 experts, x[32768,2048]f32 @ W[e][1408,2048]^T f32
// R14 = R13 (champion structure, unchanged staging/schedule/mapping) with the
// MFMA shape swapped 16x16x32 -> 32x32x16: ~20% better matrix-pipe FLOP/cyc,
// 4x fewer MFMA instructions, frag regs halved (arch VGPR stays <= 64).
#define E_ 64
#define K_ 2048
#define N_ 1408
#define BM 256
#define BN 128
#define BK 32
#define NK (K_ / BK)              // 64
#define NTHREADS 512
#define NTILE (N_ / BN)           // 11
#define LDSA (BM * BK * 2)        // 16384 B
#define LDSB (BN * BK * 2)        // 8192 B
#define LDSBUF (LDSA + LDSB)      // 24576 B
#define GRID_ 2112                // >= max J = (128+64)*11; divisible by 8

using f32x4   = __attribute__((ext_vector_type(4))) float;
using f32x16  = __attribute__((ext_vector_type(16))) float;
using bf16x8  = __attribute__((ext_vector_type(8))) short;

// Drain LDS ops only; global loads stay in flight across the barrier.
#define BAR() asm volatile("s_waitcnt lgkmcnt(0)\n\ts_barrier" ::: "memory")

__device__ __forceinline__ short f2b(float f) {
  __hip_bfloat16 h = __float2bfloat16(f);
  return __builtin_bit_cast(short, h);
}

// meta[0] = J (total jobs); meta[1+e] = jb[e] (prefix of per-expert M-tile
// counts, e=0..64); meta[66+e] = row offset of expert e. One wave, ~2 us.
__global__ void build_meta(const int* __restrict__ m_splits, int* __restrict__ meta) {
  const int e = threadIdx.x;           // 0..63
  const int m = m_splits[e];
  const int mt = (m + BM - 1) / BM;
  int sm = m, smt = mt;
#pragma unroll
  for (int d = 1; d < 64; d <<= 1) {   // inclusive wave scan
    const int vm = __shfl_up(sm, d);
    const int vt = __shfl_up(smt, d);
    if (e >= d) { sm += vm; smt += vt; }
  }
  meta[1 + e] = smt - mt;              // exclusive prefix
  meta[66 + e] = sm - m;
  if (e == 63) { meta[1 + 64] = smt; meta[0] = smt * NTILE; }
}

struct Stage { f32x4 a[2][2]; f32x4 b[2]; };

__global__ __launch_bounds__(NTHREADS, 2) void gemm_grouped(
    const float* __restrict__ x, const float* __restrict__ W,
    const int* __restrict__ m_splits, const int* __restrict__ meta,
    float* __restrict__ out) {
  __shared__ char smem[2 * LDSBUF];   // 48 KiB

  // Arithmetic job mapping: jobs enumerated e-major, nt, then M-tile t;
  // contiguous jidx chunks per XCD (bid%8 -> XCD round-robin heuristic), so
  // same-(e,nt) jobs run consecutively on one XCD and share its L2 W-slice.
  const int J = meta[0];
  const int xcd = blockIdx.x & 7;
  const int pos = blockIdx.x >> 3;
  const int q = J >> 3, r = J & 7;
  if (pos >= q + (xcd < r ? 1 : 0)) return;           // padding block
  const int jidx = xcd * q + min(xcd, r) + pos;

  int lo = 0, hi = 64;                 // largest e with jb[e]*11 <= jidx
  while (hi - lo > 1) {
    const int mid = (lo + hi) >> 1;
    if (meta[1 + mid] * NTILE <= jidx) lo = mid; else hi = mid;
  }
  const int e = lo;
  const int mt_e = meta[1 + e + 1] - meta[1 + e];
  const int rem = jidx - meta[1 + e] * NTILE;
  const int nt = rem / mt_e;
  const int t  = rem - nt * mt_e;
  const int m_e = m_splits[e];
  const int row0 = meta[66 + e] + t * BM;
  const int nrows = min(BM, m_e - t * BM);
  const int n0 = nt * BN;

  const int tid  = threadIdx.x;
  const int lane = tid & 63;
  const int w    = tid >> 6;   // 8 waves
  const int wm   = w >> 1;     // 0..3 (64-row stripe of 256)
  const int wn   = w & 1;      // 0..1 (64-col stripe of 128)

  const int strow = tid >> 2;        // staging row 0..127
  const int skc8  = (tid & 3) * 8;   // k-offset (floats) of this thread's chunk
  const int kcb   = (tid & 3) * 16;  // byte offset within 64 B LDS row

  const float* xrow = x + (size_t)row0 * K_;
  const float* wrow = W + ((size_t)e * N_ + (size_t)n0) * K_;
  const f32x4 zero4 = {0.f, 0.f, 0.f, 0.f};

  auto load_tiles = [&](int kt, Stage& st) {
    const int kbase = kt * BK + skc8;
#pragma unroll
    for (int c = 0; c < 2; ++c) {
      const int rr = c * 128 + strow;
      if (rr < nrows) {
        const float* pp = xrow + (size_t)rr * K_ + kbase;
        st.a[c][0] = *(const f32x4*)pp;
        st.a[c][1] = *(const f32x4*)(pp + 4);
      } else { st.a[c][0] = zero4; st.a[c][1] = zero4; }
    }
    const float* qq = wrow + (size_t)strow * K_ + kbase;
    st.b[0] = *(const f32x4*)qq;
    st.b[1] = *(const f32x4*)(qq + 4);
  };

  // 64 B rows, 4x16B slots; slot ^= (r>>1)&3 (identical to champion R13)
  auto write_lds = [&](int buf, const Stage& st) {
    const int base = buf * LDSBUF;
#pragma unroll
    for (int c = 0; c < 2; ++c) {
      const int rr = c * 128 + strow;
      const int off = rr * 64 + (kcb ^ (((rr >> 1) & 3) << 4));
      bf16x8 v;
#pragma unroll
      for (int i = 0; i < 4; ++i) { v[i] = f2b(st.a[c][0][i]); v[i + 4] = f2b(st.a[c][1][i]); }
      *(bf16x8*)(smem + base + off) = v;
    }
    {
      const int rr = strow;
      const int off = rr * 64 + (kcb ^ (((rr >> 1) & 3) << 4));
      bf16x8 v;
#pragma unroll
      for (int i = 0; i < 4; ++i) { v[i] = f2b(st.b[0][i]); v[i + 4] = f2b(st.b[1][i]); }
      *(bf16x8*)(smem + base + LDSA + off) = v;
    }
  };

  f32x16 acc[2][2];
#pragma unroll
  for (int i = 0; i < 2; ++i)
#pragma unroll
    for (int j = 0; j < 2; ++j)
#pragma unroll
      for (int rr = 0; rr < 16; ++rr) acc[i][j][rr] = 0.f;

  // 32x32x16 operand mapping: A row = lane&31, k = (lane>>5)*8 + j
  const int arow0 = wm * 64 + (lane & 31);
  const int brow0 = wn * 64 + (lane & 31);
  const int kgrp  = lane >> 5;           // 0..1

  auto compute = [&](int buf) {
    const int base = buf * LDSBUF;
#pragma unroll
    for (int kk = 0; kk < 2; ++kk) {
      const int sk = kk * 2 + kgrp;      // 16B slot index 0..3
      bf16x8 a0, a1, b0, b1;
      {
        const int r0 = arow0, r1 = arow0 + 32;
        a0 = *(const bf16x8*)(smem + base + r0 * 64 + ((sk ^ ((r0 >> 1) & 3)) << 4));
        a1 = *(const bf16x8*)(smem + base + r1 * 64 + ((sk ^ ((r1 >> 1) & 3)) << 4));
      }
      {
        const int r0 = brow0, r1 = brow0 + 32;
        b0 = *(const bf16x8*)(smem + base + LDSA + r0 * 64 + ((sk ^ ((r0 >> 1) & 3)) << 4));
        b1 = *(const bf16x8*)(smem + base + LDSA + r1 * 64 + ((sk ^ ((r1 >> 1) & 3)) << 4));
      }
      acc[0][0] = __builtin_amdgcn_mfma_f32_32x32x16_bf16(a0, b0, acc[0][0], 0, 0, 0);
      acc[0][1] = __builtin_amdgcn_mfma_f32_32x32x16_bf16(a0, b1, acc[0][1], 0, 0, 0);
      acc[1][0] = __builtin_amdgcn_mfma_f32_32x32x16_bf16(a1, b0, acc[1][0], 0, 0, 0);
      acc[1][1] = __builtin_amdgcn_mfma_f32_32x32x16_bf16(a1, b1, acc[1][1], 0, 0, 0);
    }
  };

  // Champion schedule (R5/R13): loads for kt+1 at top (issue-early), one
  // lgkm-only barrier per K-tile, ds_reads before ds_writes, write after
  // compute so the staging vmcnt wait sits behind the MFMA cluster.
  Stage sA;
  load_tiles(0, sA);
  write_lds(0, sA);                // prologue-only exposed vmcnt
  int cur = 0;
  for (int kt = 0; kt < NK; ++kt) {
    if (kt + 1 < NK) load_tiles(kt + 1, sA);
    BAR();                                // publishes buf `cur`
    compute(cur);
    if (kt + 1 < NK) write_lds(cur ^ 1, sA);
    cur ^= 1;
  }

  // epilogue: 32x32 C/D layout col=lane&31, row=(reg&3)+8*(reg>>2)+4*(lane>>5)
  const int crow_b = wm * 64 + 4 * (lane >> 5);
  const int ccol_b = n0 + wn * 64 + (lane & 31);
#pragma unroll
  for (int ar = 0; ar < 2; ++ar) {
#pragma unroll
    for (int rr = 0; rr < 16; ++rr) {
      const int lr = crow_b + ar * 32 + (rr & 3) + 8 * (rr >> 2);
      if (lr < nrows) {
#pragma unroll
        for (int br = 0; br < 2; ++br)
          out[(size_t)(row0 + lr) * N_ + ccol_b + br * 32] = acc[ar][br][rr];
      }
    }
  }
}

extern "C" void kernel_launch(void* const* d_in, const int* in_sizes, int n_in,
                              void* d_out, int out_size, void* d_ws, size_t ws_size,
                              hipStream_t stream) {
  const float* x        = (const float*)d_in[0];
  const float* W        = (const float*)d_in[1];
  const int*   m_splits = (const int*)d_in[2];
  float*       out      = (float*)d_out;

  int* meta = (int*)d_ws;   // 131 ints

  build_meta<<<1, 64, 0, stream>>>(m_splits, meta);
  gemm_grouped<<<GRID_, NTHREADS, 0, stream>>>(x, W, m_splits, meta, out);
}